// Round 16
// baseline (466.176 us; speedup 1.0000x reference)
//
#include <hip/hip_runtime.h>
#include <math.h>

#define BATCH 2048
#define CIN 14
#define LEN 2048
#define NB 4
#define HID 64
#define NEG 0.01f
#define L2E 1.44269504088896f

typedef __attribute__((ext_vector_type(8))) _Float16 f16x8;
typedef __attribute__((ext_vector_type(4))) float f32x4;

#define MFMA16(A, B, C) __builtin_amdgcn_mfma_f32_16x16x32_f16((A), (B), (C), 0, 0, 0)

// ---------------- Kernel A: pool (hierarchical) + conv1d(k=3,pad=1) + LeakyReLU ----------------
__device__ __forceinline__ void conv_bin(const float* __restrict__ P, int ldp, int T,
                                         int bin,
                                         const float* __restrict__ cw,
                                         const float* __restrict__ cb,
                                         float* __restrict__ dst, int tid)
{
    const float* w = cw + (size_t)bin * 4 * CIN * 3;
    const float b0 = cb[bin * 4 + 0];
    const float b1 = cb[bin * 4 + 1];
    const float b2 = cb[bin * 4 + 2];
    const float b3 = cb[bin * 4 + 3];
    for (int t = tid; t < T; t += 256) {
        float a0 = b0, a1 = b1, a2 = b2, a3 = b3;
        for (int ci = 0; ci < CIN; ++ci) {
            float pm = (t > 0)     ? P[ci * ldp + t - 1] : 0.0f;
            float p0 =               P[ci * ldp + t];
            float pp = (t < T - 1) ? P[ci * ldp + t + 1] : 0.0f;
            const float* w0 = w + (0 * CIN + ci) * 3;
            const float* w1 = w + (1 * CIN + ci) * 3;
            const float* w2 = w + (2 * CIN + ci) * 3;
            const float* w3 = w + (3 * CIN + ci) * 3;
            a0 += w0[0] * pm + w0[1] * p0 + w0[2] * pp;
            a1 += w1[0] * pm + w1[1] * p0 + w1[2] * pp;
            a2 += w2[0] * pm + w2[1] * p0 + w2[2] * pp;
            a3 += w3[0] * pm + w3[1] * p0 + w3[2] * pp;
        }
        a0 = (a0 >= 0.0f) ? a0 : NEG * a0;
        a1 = (a1 >= 0.0f) ? a1 : NEG * a1;
        a2 = (a2 >= 0.0f) ? a2 : NEG * a2;
        a3 = (a3 >= 0.0f) ? a3 : NEG * a3;
        *reinterpret_cast<float4*>(dst + (size_t)t * 4) = make_float4(a0, a1, a2, a3);
    }
}

__global__ __launch_bounds__(256) void pool_conv_kernel(
    const float* __restrict__ X, const float* __restrict__ cw,
    const float* __restrict__ cb, float* __restrict__ xc)
{
    __shared__ float Pa[CIN][512];
    __shared__ float Pb[CIN][256];
    const int b = blockIdx.x;
    const int tid = threadIdx.x;

    for (int idx = tid; idx < CIN * 512; idx += 256) {
        int c = idx >> 9, t = idx & 511;
        const float4 v = *reinterpret_cast<const float4*>(X + ((size_t)b * CIN + c) * LEN + 4 * t);
        Pa[c][t] = 0.25f * (v.x + v.y + v.z + v.w);
    }
    __syncthreads();

    conv_bin(&Pa[0][0], 512, 512, 0, cw, cb, xc + (size_t)b * 512 * 4, tid);
    for (int idx = tid; idx < CIN * 256; idx += 256) {
        int c = idx >> 8, t = idx & 255;
        Pb[c][t] = 0.5f * (Pa[c][2 * t] + Pa[c][2 * t + 1]);
    }
    __syncthreads();

    conv_bin(&Pb[0][0], 256, 256, 1, cw, cb, xc + 4194304 + (size_t)b * 256 * 4, tid);
    for (int idx = tid; idx < CIN * 128; idx += 256) {
        int c = idx >> 7, t = idx & 127;
        Pa[c][t] = 0.5f * (Pb[c][2 * t] + Pb[c][2 * t + 1]);
    }
    __syncthreads();

    conv_bin(&Pa[0][0], 512, 128, 2, cw, cb, xc + 6291456 + (size_t)b * 128 * 4, tid);
    for (int idx = tid; idx < CIN * 64; idx += 256) {
        int c = idx >> 6, t = idx & 63;
        Pb[c][t] = 0.5f * (Pa[c][2 * t] + Pa[c][2 * t + 1]);
    }
    __syncthreads();

    conv_bin(&Pb[0][0], 256, 64, 3, cw, cb, xc + 7340032 + (size_t)b * 64 * 4, tid);
}

// ---------------- Kernel B: dual-chain fp16-MFMA LSTM scan + linear head ----------------
// 128 blocks x 256 threads. Block handles TWO independent batch groups (A,B) of 16:
// every wave interleaves group A's step with group B's step — two independent
// dependency chains per in-order wave, so A's MFMA/trans latency hides under B's
// issue (and vice versa). Weights/bias registers are SHARED between groups.
// Blocks 0..63: bin 0 (groups 32*gid ..+31). Blocks 64..127: bins 1,2,3 chained.
// Per group per step: 12 MFMAs, merged-rcp activations (identical values to r13).
// One barrier per super-step (2 effective steps).

__global__ __launch_bounds__(256)
__attribute__((amdgpu_waves_per_eu(1, 1)))
void lstm_mfma_kernel(
    const float* __restrict__ xc,
    const float* __restrict__ wih, const float* __restrict__ whh,
    const float* __restrict__ bih, const float* __restrict__ bhh,
    const float* __restrict__ lw, const float* __restrict__ lb,
    float* __restrict__ out)
{
    __shared__ _Float16 hbufA[2][16][80];
    __shared__ _Float16 hbufB[2][16][80];
    __shared__ _Float16 xbufA[16][65][8];
    __shared__ _Float16 xbufB[16][65][8];
    __shared__ float    part[256];

    const int tid = threadIdx.x;
    const int w   = tid >> 6;        // wave = unit quadrant
    const int l   = tid & 63;
    const int lm  = l & 15;
    const int lg  = l >> 4;

    const int TS[NB]     = {512, 256, 128, 64};
    const size_t OFF[NB] = {0, 4194304, 6291456, 7340032};

    const bool isBin0 = (blockIdx.x < 64);
    const int gid  = isBin0 ? blockIdx.x : (blockIdx.x - 64);
    const int b0A  = gid * 32;
    const int b0B  = b0A + 16;
    const int binS = isBin0 ? 0 : 1;
    const int binE = isBin0 ? 1 : 4;

    for (int bin = binS; bin < binE; ++bin) {
        const int T = TS[bin];
        const int NW = T >> 6;
        const float* xbase = xc + OFF[bin];

        // ---- shared weights (slot order G,I,F,O), exp2-prescaled, fp16 ----
        f16x8 whiF[4][2], xwB[4];
        f32x4 biasC[4];
        const int GMAP[4] = {2, 0, 1, 3};
        #pragma unroll
        for (int gs = 0; gs < 4; ++gs) {
            const int gate = GMAP[gs];
            const float sc = (gate == 2) ? (2.0f * L2E) : (-L2E);
            const int col = bin * 256 + gate * 64 + w * 16 + lm;
            const float* wr = whh + (size_t)col * 64;
            #pragma unroll
            for (int kt = 0; kt < 2; ++kt) {
                const float* p = wr + kt * 32 + lg * 8;
                const float4 u0 = *reinterpret_cast<const float4*>(p);
                const float4 u1 = *reinterpret_cast<const float4*>(p + 4);
                f16x8 h8;
                h8[0] = (_Float16)(sc * u0.x); h8[1] = (_Float16)(sc * u0.y);
                h8[2] = (_Float16)(sc * u0.z); h8[3] = (_Float16)(sc * u0.w);
                h8[4] = (_Float16)(sc * u1.x); h8[5] = (_Float16)(sc * u1.y);
                h8[6] = (_Float16)(sc * u1.z); h8[7] = (_Float16)(sc * u1.w);
                whiF[gs][kt] = h8;
            }
            const float4 wiv = *reinterpret_cast<const float4*>(wih + (size_t)col * 4);
            f16x8 xw;
            #pragma unroll
            for (int e = 0; e < 8; ++e) xw[e] = (_Float16)0.0f;
            if (lg == 0) {
                xw[0] = (_Float16)(sc * wiv.x); xw[1] = (_Float16)(sc * wiv.y);
                xw[2] = (_Float16)(sc * wiv.z); xw[3] = (_Float16)(sc * wiv.w);
            }
            xwB[gs] = xw;
            const float bv = (bih[col] + bhh[col]) * sc;
            biasC[gs] = (f32x4){bv, bv, bv, bv};
        }

        // ---- prologue: window 0 -> xbufA/xbufB (zero-padded); zero h pingpong 0 ----
        #pragma unroll
        for (int i = 0; i < 4; ++i) {
            const int idx = tid + i * 256;
            const int bb = idx >> 6, s = idx & 63;
            const float4 xvA = *reinterpret_cast<const float4*>(
                xbase + ((size_t)(b0A + bb) * T + s) * 4);
            const float4 xvB = *reinterpret_cast<const float4*>(
                xbase + ((size_t)(b0B + bb) * T + s) * 4);
            f16x8 pk;
            pk[4] = (_Float16)0.0f; pk[5] = (_Float16)0.0f;
            pk[6] = (_Float16)0.0f; pk[7] = (_Float16)0.0f;
            pk[0] = (_Float16)xvA.x; pk[1] = (_Float16)xvA.y;
            pk[2] = (_Float16)xvA.z; pk[3] = (_Float16)xvA.w;
            *reinterpret_cast<f16x8*>(&xbufA[bb][s][0]) = pk;
            pk[0] = (_Float16)xvB.x; pk[1] = (_Float16)xvB.y;
            pk[2] = (_Float16)xvB.z; pk[3] = (_Float16)xvB.w;
            *reinterpret_cast<f16x8*>(&xbufB[bb][s][0]) = pk;
        }
        {
            _Float16* hzA = &hbufA[0][0][0];
            _Float16* hzB = &hbufB[0][0][0];
            #pragma unroll
            for (int i = 0; i < 5; ++i) {
                hzA[tid + i * 256] = (_Float16)0.0f;
                hzB[tid + i * 256] = (_Float16)0.0f;
            }
        }
        float c4A[4] = {0.0f, 0.0f, 0.0f, 0.0f};
        float c4B[4] = {0.0f, 0.0f, 0.0f, 0.0f};

        for (int tb = 0; tb < NW; ++tb) {
            float4 xrA[4], xrB[4];
            #pragma unroll 2
            for (int tw = 0; tw < 64; ++tw) {
                if (tw == 32 && tb + 1 < NW) {
                    #pragma unroll
                    for (int i = 0; i < 4; ++i) {
                        const int idx = tid + i * 256;
                        const int bb = idx >> 6, s = idx & 63;
                        xrA[i] = *reinterpret_cast<const float4*>(
                            xbase + ((size_t)(b0A + bb) * T + (tb + 1) * 64 + s) * 4);
                        xrB[i] = *reinterpret_cast<const float4*>(
                            xbase + ((size_t)(b0B + bb) * T + (tb + 1) * 64 + s) * 4);
                    }
                }
                __syncthreads();   // h(t-1) of A,B + x windows visible

                const int pp = tw & 1, pq = pp ^ 1;   // compile-time under unroll 2

                // all LDS loads issued up front (both groups)
                const f16x8 xfA  = *reinterpret_cast<const f16x8*>(&xbufA[lm][tw][0]);
                const f16x8 zhA0 = *reinterpret_cast<const f16x8*>(&hbufA[pp][lm][lg * 8]);
                const f16x8 zhA1 = *reinterpret_cast<const f16x8*>(&hbufA[pp][lm][32 + lg * 8]);
                const f16x8 xfB  = *reinterpret_cast<const f16x8*>(&xbufB[lm][tw][0]);
                const f16x8 zhB0 = *reinterpret_cast<const f16x8*>(&hbufB[pp][lm][lg * 8]);
                const f16x8 zhB1 = *reinterpret_cast<const f16x8*>(&hbufB[pp][lm][32 + lg * 8]);

                // x-MFMAs (A then B; C = shared persistent bias regs)
                f32x4 aGA = MFMA16(xfA, xwB[0], biasC[0]);
                f32x4 aIA = MFMA16(xfA, xwB[1], biasC[1]);
                f32x4 aFA = MFMA16(xfA, xwB[2], biasC[2]);
                f32x4 aOA = MFMA16(xfA, xwB[3], biasC[3]);
                f32x4 aGB = MFMA16(xfB, xwB[0], biasC[0]);
                f32x4 aIB = MFMA16(xfB, xwB[1], biasC[1]);
                f32x4 aFB = MFMA16(xfB, xwB[2], biasC[2]);
                f32x4 aOB = MFMA16(xfB, xwB[3], biasC[3]);

                // G,I chains: A then B
                aGA = MFMA16(zhA0, whiF[0][0], aGA); aGA = MFMA16(zhA1, whiF[0][1], aGA);
                aIA = MFMA16(zhA0, whiF[1][0], aIA); aIA = MFMA16(zhA1, whiF[1][1], aIA);
                aGB = MFMA16(zhB0, whiF[0][0], aGB); aGB = MFMA16(zhB1, whiF[0][1], aGB);
                aIB = MFMA16(zhB0, whiF[1][0], aIB); aIB = MFMA16(zhB1, whiF[1][1], aIB);

                // A: eG (aGA ready: 8 MFMAs ago)
                float eGA[4];
                #pragma unroll
                for (int r = 0; r < 4; ++r)
                    eGA[r] = __builtin_amdgcn_exp2f(fminf(aGA[r], 120.0f));

                // F chains
                aFA = MFMA16(zhA0, whiF[2][0], aFA); aFA = MFMA16(zhA1, whiF[2][1], aFA);
                aFB = MFMA16(zhB0, whiF[2][0], aFB); aFB = MFMA16(zhB1, whiF[2][1], aFB);

                // B: eG
                float eGB[4];
                #pragma unroll
                for (int r = 0; r < 4; ++r)
                    eGB[r] = __builtin_amdgcn_exp2f(fminf(aGB[r], 120.0f));

                // A: eI + merged i*tanh(g)
                float rigA[4];
                #pragma unroll
                for (int r = 0; r < 4; ++r) {
                    const float eI = __builtin_amdgcn_exp2f(aIA[r]);
                    rigA[r] = (eGA[r] - 1.0f) *
                              __builtin_amdgcn_rcpf((1.0f + eI) * (eGA[r] + 1.0f));
                }

                // O chains
                aOA = MFMA16(zhA0, whiF[3][0], aOA); aOA = MFMA16(zhA1, whiF[3][1], aOA);
                aOB = MFMA16(zhB0, whiF[3][0], aOB); aOB = MFMA16(zhB1, whiF[3][1], aOB);

                // B: eI + merged i*tanh(g)
                float rigB[4];
                #pragma unroll
                for (int r = 0; r < 4; ++r) {
                    const float eI = __builtin_amdgcn_exp2f(aIB[r]);
                    rigB[r] = (eGB[r] - 1.0f) *
                              __builtin_amdgcn_rcpf((1.0f + eI) * (eGB[r] + 1.0f));
                }

                const int u = w * 16 + lm;

                // A tail: eF -> c -> C2 ; oden ; hv write
                {
                    float C2[4];
                    #pragma unroll
                    for (int r = 0; r < 4; ++r) {
                        const float eF = __builtin_amdgcn_exp2f(aFA[r]);
                        c4A[r] = fmaf(__builtin_amdgcn_rcpf(1.0f + eF), c4A[r], rigA[r]);
                        C2[r] = __builtin_amdgcn_exp2f(
                            fminf((2.0f * L2E) * c4A[r], 120.0f));
                    }
                    float oden[4];
                    #pragma unroll
                    for (int r = 0; r < 4; ++r)
                        oden[r] = 1.0f + __builtin_amdgcn_exp2f(aOA[r]);
                    #pragma unroll
                    for (int r = 0; r < 4; ++r) {
                        const float hv = (C2[r] - 1.0f) *
                            __builtin_amdgcn_rcpf(oden[r] * (C2[r] + 1.0f));
                        hbufA[pq][lg * 4 + r][u] = (_Float16)hv;
                    }
                }
                // B tail
                {
                    float C2[4];
                    #pragma unroll
                    for (int r = 0; r < 4; ++r) {
                        const float eF = __builtin_amdgcn_exp2f(aFB[r]);
                        c4B[r] = fmaf(__builtin_amdgcn_rcpf(1.0f + eF), c4B[r], rigB[r]);
                        C2[r] = __builtin_amdgcn_exp2f(
                            fminf((2.0f * L2E) * c4B[r], 120.0f));
                    }
                    float oden[4];
                    #pragma unroll
                    for (int r = 0; r < 4; ++r)
                        oden[r] = 1.0f + __builtin_amdgcn_exp2f(aOB[r]);
                    #pragma unroll
                    for (int r = 0; r < 4; ++r) {
                        const float hv = (C2[r] - 1.0f) *
                            __builtin_amdgcn_rcpf(oden[r] * (C2[r] + 1.0f));
                        hbufB[pq][lg * 4 + r][u] = (_Float16)hv;
                    }
                }
            }
            if (tb + 1 < NW) {
                __syncthreads();   // all reads of this x window done
                #pragma unroll
                for (int i = 0; i < 4; ++i) {
                    const int idx = tid + i * 256;
                    const int bb = idx >> 6, s = idx & 63;
                    f16x8 pk;
                    pk[4] = (_Float16)0.0f; pk[5] = (_Float16)0.0f;
                    pk[6] = (_Float16)0.0f; pk[7] = (_Float16)0.0f;
                    pk[0] = (_Float16)xrA[i].x; pk[1] = (_Float16)xrA[i].y;
                    pk[2] = (_Float16)xrA[i].z; pk[3] = (_Float16)xrA[i].w;
                    *reinterpret_cast<f16x8*>(&xbufA[bb][s][0]) = pk;
                    pk[0] = (_Float16)xrB[i].x; pk[1] = (_Float16)xrB[i].y;
                    pk[2] = (_Float16)xrB[i].z; pk[3] = (_Float16)xrB[i].w;
                    *reinterpret_cast<f16x8*>(&xbufB[bb][s][0]) = pk;
                }
            }
        }
        __syncthreads();   // final h (pingpong 0, T even) published

        // ---- linear head: group A then group B ----
        {
            const int m = tid & 15, up = tid >> 4;
            const float* lwb = lw + bin * HID;
            float s = 0.0f;
            #pragma unroll
            for (int e = 0; e < 4; ++e) {
                const int uu = up * 4 + e;
                s = fmaf((float)hbufA[0][m][uu], lwb[uu], s);
            }
            part[tid] = s;
            __syncthreads();
            if (tid < 16) {
                float v = lb[bin];
                #pragma unroll
                for (int j = 0; j < 16; ++j) v += part[j * 16 + tid];
                out[(size_t)(b0A + tid) * NB + bin] = v;
            }
            __syncthreads();
            s = 0.0f;
            #pragma unroll
            for (int e = 0; e < 4; ++e) {
                const int uu = up * 4 + e;
                s = fmaf((float)hbufB[0][m][uu], lwb[uu], s);
            }
            part[tid] = s;
            __syncthreads();
            if (tid < 16) {
                float v = lb[bin];
                #pragma unroll
                for (int j = 0; j < 16; ++j) v += part[j * 16 + tid];
                out[(size_t)(b0B + tid) * NB + bin] = v;
            }
            __syncthreads();   // before LDS reuse by next bin
        }
    }
}

extern "C" void kernel_launch(void* const* d_in, const int* in_sizes, int n_in,
                              void* d_out, int out_size, void* d_ws, size_t ws_size,
                              hipStream_t stream) {
    const float* X   = (const float*)d_in[0];
    const float* cw  = (const float*)d_in[1];
    const float* cb  = (const float*)d_in[2];
    const float* wih = (const float*)d_in[3];
    const float* whh = (const float*)d_in[4];
    const float* bih = (const float*)d_in[5];
    const float* bhh = (const float*)d_in[6];
    const float* lw  = (const float*)d_in[7];
    const float* lb  = (const float*)d_in[8];
    float* out = (float*)d_out;
    float* xc  = (float*)d_ws;   // 7,864,320 floats = 31.5 MB

    pool_conv_kernel<<<BATCH, 256, 0, stream>>>(X, cw, cb, xc);
    lstm_mfma_kernel<<<128, 256, 0, stream>>>(xc, wih, whh, bih, bhh, lw, lb, out);
}

// Round 17
// 293.474 us; speedup vs baseline: 1.5885x; 1.5885x over previous
//
#include <hip/hip_runtime.h>
#include <math.h>

#define BATCH 2048
#define CIN 14
#define LEN 2048
#define NB 4
#define HID 64
#define NEG 0.01f
#define L2E 1.44269504088896f

typedef __attribute__((ext_vector_type(8))) _Float16 f16x8;
typedef __attribute__((ext_vector_type(4))) float f32x4;

// ---------------- Kernel A: pool (hierarchical) + conv1d(k=3,pad=1) + LeakyReLU ----------------
__device__ __forceinline__ void conv_bin(const float* __restrict__ P, int ldp, int T,
                                         int bin,
                                         const float* __restrict__ cw,
                                         const float* __restrict__ cb,
                                         float* __restrict__ dst, int tid)
{
    const float* w = cw + (size_t)bin * 4 * CIN * 3;
    const float b0 = cb[bin * 4 + 0];
    const float b1 = cb[bin * 4 + 1];
    const float b2 = cb[bin * 4 + 2];
    const float b3 = cb[bin * 4 + 3];
    for (int t = tid; t < T; t += 256) {
        float a0 = b0, a1 = b1, a2 = b2, a3 = b3;
        for (int ci = 0; ci < CIN; ++ci) {
            float pm = (t > 0)     ? P[ci * ldp + t - 1] : 0.0f;
            float p0 =               P[ci * ldp + t];
            float pp = (t < T - 1) ? P[ci * ldp + t + 1] : 0.0f;
            const float* w0 = w + (0 * CIN + ci) * 3;
            const float* w1 = w + (1 * CIN + ci) * 3;
            const float* w2 = w + (2 * CIN + ci) * 3;
            const float* w3 = w + (3 * CIN + ci) * 3;
            a0 += w0[0] * pm + w0[1] * p0 + w0[2] * pp;
            a1 += w1[0] * pm + w1[1] * p0 + w1[2] * pp;
            a2 += w2[0] * pm + w2[1] * p0 + w2[2] * pp;
            a3 += w3[0] * pm + w3[1] * p0 + w3[2] * pp;
        }
        a0 = (a0 >= 0.0f) ? a0 : NEG * a0;
        a1 = (a1 >= 0.0f) ? a1 : NEG * a1;
        a2 = (a2 >= 0.0f) ? a2 : NEG * a2;
        a3 = (a3 >= 0.0f) ? a3 : NEG * a3;
        *reinterpret_cast<float4*>(dst + (size_t)t * 4) = make_float4(a0, a1, a2, a3);
    }
}

__global__ __launch_bounds__(256) void pool_conv_kernel(
    const float* __restrict__ X, const float* __restrict__ cw,
    const float* __restrict__ cb, float* __restrict__ xc)
{
    __shared__ float Pa[CIN][512];
    __shared__ float Pb[CIN][256];
    const int b = blockIdx.x;
    const int tid = threadIdx.x;

    for (int idx = tid; idx < CIN * 512; idx += 256) {
        int c = idx >> 9, t = idx & 511;
        const float4 v = *reinterpret_cast<const float4*>(X + ((size_t)b * CIN + c) * LEN + 4 * t);
        Pa[c][t] = 0.25f * (v.x + v.y + v.z + v.w);
    }
    __syncthreads();

    conv_bin(&Pa[0][0], 512, 512, 0, cw, cb, xc + (size_t)b * 512 * 4, tid);
    for (int idx = tid; idx < CIN * 256; idx += 256) {
        int c = idx >> 8, t = idx & 255;
        Pb[c][t] = 0.5f * (Pa[c][2 * t] + Pa[c][2 * t + 1]);
    }
    __syncthreads();

    conv_bin(&Pb[0][0], 256, 256, 1, cw, cb, xc + 4194304 + (size_t)b * 256 * 4, tid);
    for (int idx = tid; idx < CIN * 128; idx += 256) {
        int c = idx >> 7, t = idx & 127;
        Pa[c][t] = 0.5f * (Pb[c][2 * t] + Pb[c][2 * t + 1]);
    }
    __syncthreads();

    conv_bin(&Pa[0][0], 512, 128, 2, cw, cb, xc + 6291456 + (size_t)b * 128 * 4, tid);
    for (int idx = tid; idx < CIN * 64; idx += 256) {
        int c = idx >> 6, t = idx & 63;
        Pb[c][t] = 0.5f * (Pa[c][2 * t] + Pa[c][2 * t + 1]);
    }
    __syncthreads();

    conv_bin(&Pb[0][0], 256, 64, 3, cw, cb, xc + 7340032 + (size_t)b * 64 * 4, tid);
}

// ---------------- Kernel B: fp16-MFMA LSTM scan + linear head ----------------
// FINAL (r15): pure fp16, 12 MFMAs/step, r10 gate-interleaved schedule,
// 1 barrier/step, 4 waves x 16 batch, bin0 on blocks 0..127, bins 1-3 chained
// on blocks 128..255. Issue-bound at ~1110 cyc/step on a single in-order wave;
// measured-refuted alternatives: lockstep wave-split (r7/r8), cross-barrier
// seeding (r11), reorder + raw barriers (r12), dual-chain ILP / co-residency
// (r16: per-chain cost 2I > I+L since issue I ~850 > exposed latency L ~260).

__global__ __launch_bounds__(256)
__attribute__((amdgpu_waves_per_eu(1, 1)))
void lstm_mfma_kernel(
    const float* __restrict__ xc,
    const float* __restrict__ wih, const float* __restrict__ whh,
    const float* __restrict__ bih, const float* __restrict__ bhh,
    const float* __restrict__ lw, const float* __restrict__ lb,
    float* __restrict__ out)
{
    __shared__ _Float16 hbuf[2][16][80];   // [pingpong][row][unit], 160B rows
    __shared__ _Float16 xbuf[16][65][8];   // [batch][step][4ch + 4 zeros], 16B entries
    __shared__ float    part[256];

    const int tid = threadIdx.x;
    const int w   = tid >> 6;        // wave = unit quadrant
    const int l   = tid & 63;
    const int lm  = l & 15;
    const int lg  = l >> 4;

    const int TS[NB]     = {512, 256, 128, 64};
    const size_t OFF[NB] = {0, 4194304, 6291456, 7340032};

    const bool isBin0 = (blockIdx.x < 128);
    const int b0   = (isBin0 ? blockIdx.x : (blockIdx.x - 128)) * 16;
    const int binS = isBin0 ? 0 : 1;
    const int binE = isBin0 ? 1 : 4;

    for (int bin = binS; bin < binE; ++bin) {
        const int T = TS[bin];
        const int NW = T >> 6;
        const float* xbase = xc + OFF[bin];

        // ---- weights (slot order G,I,F,O), exp2-prescaled, fp16 ----
        f16x8 whiF[4][2], xwB[4];
        f32x4 biasC[4];
        const int GMAP[4] = {2, 0, 1, 3};
        #pragma unroll
        for (int gs = 0; gs < 4; ++gs) {
            const int gate = GMAP[gs];
            const float sc = (gate == 2) ? (2.0f * L2E) : (-L2E);
            const int col = bin * 256 + gate * 64 + w * 16 + lm;
            const float* wr = whh + (size_t)col * 64;
            #pragma unroll
            for (int kt = 0; kt < 2; ++kt) {
                const float* p = wr + kt * 32 + lg * 8;
                const float4 u0 = *reinterpret_cast<const float4*>(p);
                const float4 u1 = *reinterpret_cast<const float4*>(p + 4);
                f16x8 h8;
                h8[0] = (_Float16)(sc * u0.x); h8[1] = (_Float16)(sc * u0.y);
                h8[2] = (_Float16)(sc * u0.z); h8[3] = (_Float16)(sc * u0.w);
                h8[4] = (_Float16)(sc * u1.x); h8[5] = (_Float16)(sc * u1.y);
                h8[6] = (_Float16)(sc * u1.z); h8[7] = (_Float16)(sc * u1.w);
                whiF[gs][kt] = h8;
            }
            const float4 wiv = *reinterpret_cast<const float4*>(wih + (size_t)col * 4);
            f16x8 xw;
            #pragma unroll
            for (int e = 0; e < 8; ++e) xw[e] = (_Float16)0.0f;
            if (lg == 0) {
                xw[0] = (_Float16)(sc * wiv.x); xw[1] = (_Float16)(sc * wiv.y);
                xw[2] = (_Float16)(sc * wiv.z); xw[3] = (_Float16)(sc * wiv.w);
            }
            xwB[gs] = xw;
            const float bv = (bih[col] + bhh[col]) * sc;
            biasC[gs] = (f32x4){bv, bv, bv, bv};
        }

        // ---- prologue: window 0 -> xbuf (zero-padded); zero h pingpong 0 ----
        #pragma unroll
        for (int i = 0; i < 4; ++i) {
            const int idx = tid + i * 256;
            const int bb = idx >> 6, s = idx & 63;
            const float4 xv = *reinterpret_cast<const float4*>(
                xbase + ((size_t)(b0 + bb) * T + s) * 4);
            f16x8 pk;
            pk[0] = (_Float16)xv.x; pk[1] = (_Float16)xv.y;
            pk[2] = (_Float16)xv.z; pk[3] = (_Float16)xv.w;
            pk[4] = (_Float16)0.0f; pk[5] = (_Float16)0.0f;
            pk[6] = (_Float16)0.0f; pk[7] = (_Float16)0.0f;
            *reinterpret_cast<f16x8*>(&xbuf[bb][s][0]) = pk;
        }
        {
            _Float16* hz = &hbuf[0][0][0];
            #pragma unroll
            for (int i = 0; i < 5; ++i) hz[tid + i * 256] = (_Float16)0.0f;
        }
        float c4[4] = {0.0f, 0.0f, 0.0f, 0.0f};

        for (int tb = 0; tb < NW; ++tb) {
            float4 xr[4];
            #pragma unroll 2
            for (int tw = 0; tw < 64; ++tw) {
                if (tw == 32 && tb + 1 < NW) {
                    #pragma unroll
                    for (int i = 0; i < 4; ++i) {
                        const int idx = tid + i * 256;
                        const int bb = idx >> 6, s = idx & 63;
                        xr[i] = *reinterpret_cast<const float4*>(
                            xbase + ((size_t)(b0 + bb) * T + (tb + 1) * 64 + s) * 4);
                    }
                }
                __syncthreads();   // h(t-1) + x window visible

                const int pp = tw & 1, pq = pp ^ 1;   // compile-time under unroll 2

                // all LDS loads issued up front (xfv = single b128, zero-padded)
                const f16x8 xfv = *reinterpret_cast<const f16x8*>(&xbuf[lm][tw][0]);
                const f16x8 zh0 = *reinterpret_cast<const f16x8*>(&hbuf[pp][lm][lg * 8]);
                const f16x8 zh1 = *reinterpret_cast<const f16x8*>(&hbuf[pp][lm][32 + lg * 8]);

                // 4 x-MFMAs first (dep: xfv only; C = persistent bias regs)
                f32x4 aG = __builtin_amdgcn_mfma_f32_16x16x32_f16(xfv, xwB[0], biasC[0], 0, 0, 0);
                f32x4 aI = __builtin_amdgcn_mfma_f32_16x16x32_f16(xfv, xwB[1], biasC[1], 0, 0, 0);
                f32x4 aF = __builtin_amdgcn_mfma_f32_16x16x32_f16(xfv, xwB[2], biasC[2], 0, 0, 0);
                f32x4 aO = __builtin_amdgcn_mfma_f32_16x16x32_f16(xfv, xwB[3], biasC[3], 0, 0, 0);

                // G chain (2), I chain (2)
                aG = __builtin_amdgcn_mfma_f32_16x16x32_f16(zh0, whiF[0][0], aG, 0, 0, 0);
                aG = __builtin_amdgcn_mfma_f32_16x16x32_f16(zh1, whiF[0][1], aG, 0, 0, 0);
                aI = __builtin_amdgcn_mfma_f32_16x16x32_f16(zh0, whiF[1][0], aI, 0, 0, 0);
                aI = __builtin_amdgcn_mfma_f32_16x16x32_f16(zh1, whiF[1][1], aI, 0, 0, 0);

                // G exp2s (overlap F chain)
                float eG[4];
                #pragma unroll
                for (int r = 0; r < 4; ++r)
                    eG[r] = __builtin_amdgcn_exp2f(fminf(aG[r], 120.0f));

                // F chain (2)
                aF = __builtin_amdgcn_mfma_f32_16x16x32_f16(zh0, whiF[2][0], aF, 0, 0, 0);
                aF = __builtin_amdgcn_mfma_f32_16x16x32_f16(zh1, whiF[2][1], aF, 0, 0, 0);

                // I exp2s + merged i*tanh(g) (overlap O chain)
                float rig[4];
                #pragma unroll
                for (int r = 0; r < 4; ++r) {
                    const float eI = __builtin_amdgcn_exp2f(aI[r]);
                    rig[r] = (eG[r] - 1.0f) *
                             __builtin_amdgcn_rcpf((1.0f + eI) * (eG[r] + 1.0f));
                }

                // O chain (2)
                aO = __builtin_amdgcn_mfma_f32_16x16x32_f16(zh0, whiF[3][0], aO, 0, 0, 0);
                aO = __builtin_amdgcn_mfma_f32_16x16x32_f16(zh1, whiF[3][1], aO, 0, 0, 0);

                // eF -> c -> C2 (overlap O chain completion)
                float C2[4];
                #pragma unroll
                for (int r = 0; r < 4; ++r) {
                    const float eF = __builtin_amdgcn_exp2f(aF[r]);
                    c4[r] = fmaf(__builtin_amdgcn_rcpf(1.0f + eF), c4[r], rig[r]);
                    C2[r] = __builtin_amdgcn_exp2f(
                        fminf((2.0f * L2E) * c4[r], 120.0f));
                }

                // eO pipeline ahead of the dependent hv chains
                float oden[4];
                #pragma unroll
                for (int r = 0; r < 4; ++r)
                    oden[r] = 1.0f + __builtin_amdgcn_exp2f(aO[r]);

                // exposed tail: hv -> single-plane write
                const int u = w * 16 + lm;
                #pragma unroll
                for (int r = 0; r < 4; ++r) {
                    const float hv = (C2[r] - 1.0f) *
                        __builtin_amdgcn_rcpf(oden[r] * (C2[r] + 1.0f));
                    hbuf[pq][lg * 4 + r][u] = (_Float16)hv;
                }
            }
            if (tb + 1 < NW) {
                __syncthreads();   // all reads of this x window done
                #pragma unroll
                for (int i = 0; i < 4; ++i) {
                    const int idx = tid + i * 256;
                    const int bb = idx >> 6, s = idx & 63;
                    const float4 xv = xr[i];
                    f16x8 pk;
                    pk[0] = (_Float16)xv.x; pk[1] = (_Float16)xv.y;
                    pk[2] = (_Float16)xv.z; pk[3] = (_Float16)xv.w;
                    pk[4] = (_Float16)0.0f; pk[5] = (_Float16)0.0f;
                    pk[6] = (_Float16)0.0f; pk[7] = (_Float16)0.0f;
                    *reinterpret_cast<f16x8*>(&xbuf[bb][s][0]) = pk;
                }
            }
        }
        __syncthreads();   // final h (pingpong 0, T even) published

        // ---- linear head: out[b][bin] = h[b]·lw[bin] + lb[bin] ----
        {
            const int m = tid & 15, up = tid >> 4;
            const float* lwb = lw + bin * HID;
            float s = 0.0f;
            #pragma unroll
            for (int e = 0; e < 4; ++e) {
                const int uu = up * 4 + e;
                s = fmaf((float)hbuf[0][m][uu], lwb[uu], s);
            }
            part[tid] = s;
            __syncthreads();
            if (tid < 16) {
                float v = lb[bin];
                #pragma unroll
                for (int j = 0; j < 16; ++j) v += part[j * 16 + tid];
                out[(size_t)(b0 + tid) * NB + bin] = v;
            }
            __syncthreads();   // before LDS reuse by next bin
        }
    }
}

extern "C" void kernel_launch(void* const* d_in, const int* in_sizes, int n_in,
                              void* d_out, int out_size, void* d_ws, size_t ws_size,
                              hipStream_t stream) {
    const float* X   = (const float*)d_in[0];
    const float* cw  = (const float*)d_in[1];
    const float* cb  = (const float*)d_in[2];
    const float* wih = (const float*)d_in[3];
    const float* whh = (const float*)d_in[4];
    const float* bih = (const float*)d_in[5];
    const float* bhh = (const float*)d_in[6];
    const float* lw  = (const float*)d_in[7];
    const float* lb  = (const float*)d_in[8];
    float* out = (float*)d_out;
    float* xc  = (float*)d_ws;   // 7,864,320 floats = 31.5 MB

    pool_conv_kernel<<<BATCH, 256, 0, stream>>>(X, cw, cb, xc);
    lstm_mfma_kernel<<<256, 256, 0, stream>>>(xc, wih, whh, bih, bhh, lw, lb, out);
}